// Round 11
// baseline (581.198 us; speedup 1.0000x reference)
//
#include <hip/hip_runtime.h>

#define BATCH 65536

typedef float f32x4 __attribute__((ext_vector_type(4)));
typedef _Float16 f16x8 __attribute__((ext_vector_type(8)));

__device__ __forceinline__ void async_ld16(const void* g, void* l) {
  __builtin_amdgcn_global_load_lds(
      (const __attribute__((address_space(1))) void*)g,
      (__attribute__((address_space(3))) void*)l, 16, 0, 0);
}

__device__ __forceinline__ float act_f(float x, float a0, float a1, float a2,
                                       float a3, float a4) {
  float ax = fabsf(x);
  float e = __builtin_amdgcn_exp2f(ax * -2.8853900817779268f);
  float th = (1.0f - e) * __builtin_amdgcn_rcpf(1.0f + e);
  th = copysignf(th, x);
  float arg = fmaf(a1, x, a2);
  float rev = arg * 0.15915494309189535f;
  rev -= floorf(rev);
  float s = __builtin_amdgcn_sinf(rev);
  return fmaf(a3, x, fmaf(a0 * th, s, a4));
}

// split + transpose weights: W[K][N] fp32 -> Wt_hi/lo[N][K] fp16.
// i indexes the OUTPUT (n,k): writes coalesced, reads strided.
__global__ __launch_bounds__(256) void splitT_k(const float* __restrict__ W,
                                                _Float16* __restrict__ hi,
                                                _Float16* __restrict__ lo,
                                                int K, int N) {
  const int i = blockIdx.x * 256 + threadIdx.x;
  if (i >= K * N) return;
  const int n = i / K, k = i % K;
  const float w = W[(size_t)k * N + n];
  const _Float16 h = (_Float16)w;
  hi[i] = h;
  lo[i] = (_Float16)(w - (float)h);
}

__device__ __forceinline__ f32x4 mfma3(f16x8 ah, f16x8 al, f16x8 bh, f16x8 bl,
                                       f32x4 c) {
  c = __builtin_amdgcn_mfma_f32_16x16x32_f16(ah, bh, c, 0, 0, 0);
  c = __builtin_amdgcn_mfma_f32_16x16x32_f16(ah, bl, c, 0, 0, 0);
  c = __builtin_amdgcn_mfma_f32_16x16x32_f16(al, bh, c, 0, 0, 0);
  return c;
}

// C = A @ B, block tile 64 rows x 256 cols, BK=32 (the r8 verified geometry).
// 4 waves as 2x2; wave tile 32x128 (2 m-tiles x 8 n-tiles).
// 3-product compensation (Ahi*Bhi + Ahi*Blo + Alo*Bhi, fp32 acc).
// Epilogue: bias + activation; FINAL -> in-block softmax then fp32 out;
// else hi/lo fp16 planes written COALESCED via an LDS (sB, dead after the
// K-loop) round-trip: fragment-order scatter into LDS, then full-row 16-B
// stores (each 512-B row = 4 full cachelines -> no read-for-ownership).
// Values/layout bit-identical to the scattered-store version.
template <bool AF32, bool FINAL>
__global__ __launch_bounds__(256, 4) void gemm_act(
    const float* __restrict__ Af, const _Float16* __restrict__ Ahi,
    const _Float16* __restrict__ Alo, const _Float16* __restrict__ Bhi,
    const _Float16* __restrict__ Blo, const float* __restrict__ bias,
    const float* __restrict__ ap, _Float16* __restrict__ Chi,
    _Float16* __restrict__ Clo, float* __restrict__ Cout, int K, int N) {
  // sA: 8 KB = fp32 A tile 64x32 (AF32) or 2 fp16 planes 64x32 each
  // sB: 32 KB = 2 fp16 planes 256x32 (K-loop); y-plane 64x256 (epilogue)
  __shared__ __align__(16) _Float16 sA[4096];
  __shared__ __align__(16) _Float16 sB[16384];

  const int tid = threadIdx.x;
  const int wv = tid >> 6;
  const int lane = tid & 63;
  const int wm = wv >> 1, wn = wv & 1;
  const int m16 = lane & 15, quad = lane >> 4;
  const int col0 = blockIdx.x * 256;
  const int row0 = blockIdx.y * 64;

  f32x4 acc[2][8];
  const f32x4 zero = {0.f, 0.f, 0.f, 0.f};
#pragma unroll
  for (int i = 0; i < 2; ++i)
#pragma unroll
    for (int j = 0; j < 8; ++j) acc[i][j] = zero;

  const int nk = K >> 5;
  for (int kt = 0; kt < nk; ++kt) {
    const int k0 = kt << 5;
    // ---- stage A ----
    if (AF32) {
      // 8 chunks of 1KB (8 rows x 128B); wave stages chunks 2wv, 2wv+1
      float* sAf = (float*)sA;
#pragma unroll
      for (int t = 0; t < 2; ++t) {
        const int c = wv * 2 + t;
        const int r = c * 8 + (lane >> 3);
        const size_t ga = (size_t)(row0 + r) * K + k0 + (lane & 7) * 4;
        async_ld16(Af + ga, (void*)&sAf[c * 256]);
      }
    } else {
      // per plane: 4 chunks (16 rows x 64B); wave stages chunk wv of each
      const int r = wv * 16 + (lane >> 2);
      const size_t ga = (size_t)(row0 + r) * K + k0 + (lane & 3) * 8;
      async_ld16(Ahi + ga, (void*)&sA[wv * 512]);
      async_ld16(Alo + ga, (void*)&sA[2048 + wv * 512]);
    }
    // ---- stage B: per plane 16 chunks (16 cols x 64B); wave stages 4 ----
#pragma unroll
    for (int t = 0; t < 4; ++t) {
      const int c = wv * 4 + t;
      const int col = c * 16 + (lane >> 2);
      const size_t gb = (size_t)(col0 + col) * K + k0 + (lane & 3) * 8;
      async_ld16(Bhi + gb, (void*)&sB[c * 512]);
      async_ld16(Blo + gb, (void*)&sB[8192 + c * 512]);
    }
    __syncthreads();

    // ---- A fragments ----
    f16x8 ah[2], al[2];
#pragma unroll
    for (int tm = 0; tm < 2; ++tm) {
      const int arow = wm * 32 + tm * 16 + m16;
      if (AF32) {
        const float* pa = (const float*)sA + arow * 32 + quad * 8;
        const f32x4 x0 = *(const f32x4*)pa;
        const f32x4 x1 = *(const f32x4*)(pa + 4);
#pragma unroll
        for (int j = 0; j < 4; ++j) {
          const _Float16 h0 = (_Float16)x0[j];
          ah[tm][j] = h0;
          al[tm][j] = (_Float16)(x0[j] - (float)h0);
          const _Float16 h1 = (_Float16)x1[j];
          ah[tm][4 + j] = h1;
          al[tm][4 + j] = (_Float16)(x1[j] - (float)h1);
        }
      } else {
        ah[tm] = *(const f16x8*)&sA[arow * 32 + quad * 8];
        al[tm] = *(const f16x8*)&sA[2048 + arow * 32 + quad * 8];
      }
    }
    // ---- B fragments + MFMA, n-tiles streamed ----
#pragma unroll
    for (int tn = 0; tn < 8; ++tn) {
      const int bcol = wn * 128 + tn * 16 + m16;
      const f16x8 bh = *(const f16x8*)&sB[bcol * 32 + quad * 8];
      const f16x8 bl = *(const f16x8*)&sB[8192 + bcol * 32 + quad * 8];
#pragma unroll
      for (int tm = 0; tm < 2; ++tm)
        acc[tm][tn] = mfma3(ah[tm], al[tm], bh, bl, acc[tm][tn]);
    }
    __syncthreads();
  }

  // ---- epilogue: C/D layout col=lane&15, row=quad*4+reg ----
  if (FINAL) {
    // bias + activation in place, then in-block softmax over 256 cols.
    float* const redf = (float*)sA;        // [2 wn][64 rows]
    float* const rowm = (float*)sA + 128;  // [64] row max
    float* const rowi = (float*)sA + 192;  // [64] row 1/sum
#pragma unroll
    for (int tn = 0; tn < 8; ++tn) {
      const int col = col0 + wn * 128 + tn * 16 + m16;
      const float bs = bias[col];
      const float p0 = ap[col * 5 + 0];
      const float p1 = ap[col * 5 + 1];
      const float p2 = ap[col * 5 + 2];
      const float p3 = ap[col * 5 + 3];
      const float p4 = ap[col * 5 + 4];
#pragma unroll
      for (int tm = 0; tm < 2; ++tm)
#pragma unroll
        for (int r = 0; r < 4; ++r)
          acc[tm][tn][r] = act_f(acc[tm][tn][r] + bs, p0, p1, p2, p3, p4);
    }
#pragma unroll
    for (int tm = 0; tm < 2; ++tm)
#pragma unroll
      for (int r = 0; r < 4; ++r) {
        float m = acc[tm][0][r];
#pragma unroll
        for (int tn = 1; tn < 8; ++tn) m = fmaxf(m, acc[tm][tn][r]);
#pragma unroll
        for (int off = 1; off < 16; off <<= 1) m = fmaxf(m, __shfl_xor(m, off));
        if (m16 == 0) {
          const int rowl = wm * 32 + tm * 16 + quad * 4 + r;
          redf[wn * 64 + rowl] = m;
        }
      }
    __syncthreads();
    if (tid < 64) rowm[tid] = fmaxf(redf[tid], redf[64 + tid]);
    __syncthreads();
#pragma unroll
    for (int tm = 0; tm < 2; ++tm)
#pragma unroll
      for (int r = 0; r < 4; ++r) {
        const int rowl = wm * 32 + tm * 16 + quad * 4 + r;
        const float m = rowm[rowl];
        float s = 0.f;
#pragma unroll
        for (int tn = 0; tn < 8; ++tn) {
          const float e = __builtin_amdgcn_exp2f((acc[tm][tn][r] - m) *
                                                 1.4426950408889634f);
          acc[tm][tn][r] = e;
          s += e;
        }
#pragma unroll
        for (int off = 1; off < 16; off <<= 1) s += __shfl_xor(s, off);
        if (m16 == 0) redf[wn * 64 + rowl] = s;
      }
    __syncthreads();
    if (tid < 64) rowi[tid] = __builtin_amdgcn_rcpf(redf[tid] + redf[64 + tid]);
    __syncthreads();
#pragma unroll
    for (int tm = 0; tm < 2; ++tm)
#pragma unroll
      for (int r = 0; r < 4; ++r) {
        const int rowl = wm * 32 + tm * 16 + quad * 4 + r;
        const float inv = rowi[rowl];
#pragma unroll
        for (int tn = 0; tn < 8; ++tn) {
          const int col = col0 + wn * 128 + tn * 16 + m16;
          Cout[(size_t)(row0 + rowl) * 256 + col] = acc[tm][tn][r] * inv;
        }
      }
  } else {
    // bias + activation once into acc (y values), then two coalesced
    // plane passes through sB (64x256 fp16 = 32 KB, dead after K-loop).
#pragma unroll
    for (int tn = 0; tn < 8; ++tn) {
      const int col = col0 + wn * 128 + tn * 16 + m16;
      const float bs = bias[col];
      const float p0 = ap[col * 5 + 0];
      const float p1 = ap[col * 5 + 1];
      const float p2 = ap[col * 5 + 2];
      const float p3 = ap[col * 5 + 3];
      const float p4 = ap[col * 5 + 4];
#pragma unroll
      for (int tm = 0; tm < 2; ++tm)
#pragma unroll
        for (int r = 0; r < 4; ++r)
          acc[tm][tn][r] = act_f(acc[tm][tn][r] + bs, p0, p1, p2, p3, p4);
    }
    const int rowl_o = tid >> 2;            // write-out row 0..63
    const int seg_o = (tid & 3) * 64;       // write-out col segment
    // ---- pass 1: hi plane ----
#pragma unroll
    for (int tn = 0; tn < 8; ++tn) {
      const int cl = wn * 128 + tn * 16 + m16;
#pragma unroll
      for (int tm = 0; tm < 2; ++tm)
#pragma unroll
        for (int r = 0; r < 4; ++r) {
          const int rowl = wm * 32 + tm * 16 + quad * 4 + r;
          sB[rowl * 256 + cl] = (_Float16)acc[tm][tn][r];
        }
    }
    __syncthreads();
    {
      const _Float16* src = &sB[rowl_o * 256 + seg_o];
      _Float16* dst = Chi + (size_t)(row0 + rowl_o) * N + col0 + seg_o;
#pragma unroll
      for (int t = 0; t < 8; ++t)
        *(f16x8*)(dst + t * 8) = *(const f16x8*)(src + t * 8);
    }
    __syncthreads();
    // ---- pass 2: lo plane ----
#pragma unroll
    for (int tn = 0; tn < 8; ++tn) {
      const int cl = wn * 128 + tn * 16 + m16;
#pragma unroll
      for (int tm = 0; tm < 2; ++tm)
#pragma unroll
        for (int r = 0; r < 4; ++r) {
          const int rowl = wm * 32 + tm * 16 + quad * 4 + r;
          const float y = acc[tm][tn][r];
          sB[rowl * 256 + cl] = (_Float16)(y - (float)(_Float16)y);
        }
    }
    __syncthreads();
    {
      const _Float16* src = &sB[rowl_o * 256 + seg_o];
      _Float16* dst = Clo + (size_t)(row0 + rowl_o) * N + col0 + seg_o;
#pragma unroll
      for (int t = 0; t < 8; ++t)
        *(f16x8*)(dst + t * 8) = *(const f16x8*)(src + t * 8);
    }
  }
}

extern "C" void kernel_launch(void* const* d_in, const int* in_sizes, int n_in,
                              void* d_out, int out_size, void* d_ws,
                              size_t ws_size, hipStream_t stream) {
  const float* data = (const float*)d_in[0];
  const float* W1 = (const float*)d_in[1];
  const float* b1 = (const float*)d_in[2];
  const float* a1 = (const float*)d_in[3];
  const float* W2 = (const float*)d_in[4];
  const float* b2 = (const float*)d_in[5];
  const float* a2 = (const float*)d_in[6];
  const float* W3 = (const float*)d_in[7];
  const float* b3 = (const float*)d_in[8];
  const float* a3 = (const float*)d_in[9];
  float* out = (float*)d_out;

  char* ws = (char*)d_ws;
  const size_t KB = 1024, MB = 1024 * 1024;
  _Float16* w1hi = (_Float16*)(ws + 0 * KB);  // Wt1[512][256]
  _Float16* w1lo = (_Float16*)(ws + 256 * KB);
  _Float16* w2hi = (_Float16*)(ws + 512 * KB);  // Wt2[512][512]
  _Float16* w2lo = (_Float16*)(ws + 1024 * KB);
  _Float16* w3hi = (_Float16*)(ws + 1536 * KB);  // Wt3[256][512]
  _Float16* w3lo = (_Float16*)(ws + 1792 * KB);
  // h1 hi/lo: 65536x512 fp16 = 64 MB each; h2lo 64 MB; h2hi lives in d_out
  // (row-disjoint final blocks; epilogue writes after all K-loop reads)
  _Float16* h1hi = (_Float16*)(ws + 2 * MB);
  _Float16* h1lo = (_Float16*)(ws + 2 * MB + (size_t)BATCH * 512 * 2);
  _Float16* h2lo = (_Float16*)(ws + 2 * MB + (size_t)BATCH * 512 * 4);
  _Float16* h2hi = (_Float16*)d_out;

  splitT_k<<<(256 * 512 + 255) / 256, 256, 0, stream>>>(W1, w1hi, w1lo, 256, 512);
  splitT_k<<<(512 * 512 + 255) / 256, 256, 0, stream>>>(W2, w2hi, w2lo, 512, 512);
  splitT_k<<<(512 * 256 + 255) / 256, 256, 0, stream>>>(W3, w3hi, w3lo, 512, 256);

  // grid: x = N-tiles (fastest -> strip-mates dispatch-adjacent, L3-hot A),
  //       y = 64-row M-strips
  gemm_act<true, false><<<dim3(2, BATCH / 64), 256, 0, stream>>>(
      data, nullptr, nullptr, w1hi, w1lo, b1, a1, h1hi, h1lo, nullptr, 256, 512);
  gemm_act<false, false><<<dim3(2, BATCH / 64), 256, 0, stream>>>(
      nullptr, h1hi, h1lo, w2hi, w2lo, b2, a2, h2hi, h2lo, nullptr, 512, 512);
  gemm_act<false, true><<<dim3(1, BATCH / 64), 256, 0, stream>>>(
      nullptr, h2hi, h2lo, w3hi, w3lo, b3, a3, nullptr, nullptr, out, 512, 256);
}

// Round 12
// 420.905 us; speedup vs baseline: 1.3808x; 1.3808x over previous
//
#include <hip/hip_runtime.h>

#define BATCH 65536

typedef float f32x4 __attribute__((ext_vector_type(4)));
typedef _Float16 f16x8 __attribute__((ext_vector_type(8)));

__device__ __forceinline__ void async_ld16(const void* g, void* l) {
  __builtin_amdgcn_global_load_lds(
      (const __attribute__((address_space(1))) void*)g,
      (__attribute__((address_space(3))) void*)l, 16, 0, 0);
}

__device__ __forceinline__ float act_f(float x, float a0, float a1, float a2,
                                       float a3, float a4) {
  float ax = fabsf(x);
  float e = __builtin_amdgcn_exp2f(ax * -2.8853900817779268f);
  float th = (1.0f - e) * __builtin_amdgcn_rcpf(1.0f + e);
  th = copysignf(th, x);
  float arg = fmaf(a1, x, a2);
  float rev = arg * 0.15915494309189535f;
  rev -= floorf(rev);
  float s = __builtin_amdgcn_sinf(rev);
  return fmaf(a3, x, fmaf(a0 * th, s, a4));
}

// merged split+transpose for all three weight matrices in one launch:
// W[K][N] fp32 -> Wt_hi/lo[N][K] fp16, output-indexed (coalesced writes).
__global__ __launch_bounds__(256) void splitT3(
    const float* __restrict__ W1, _Float16* __restrict__ h1,
    _Float16* __restrict__ l1, const float* __restrict__ W2,
    _Float16* __restrict__ h2, _Float16* __restrict__ l2,
    const float* __restrict__ W3, _Float16* __restrict__ h3,
    _Float16* __restrict__ l3) {
  const int i = blockIdx.x * 256 + threadIdx.x;
  const float* W;
  _Float16 *hi, *lo;
  int idx, K, N;
  if (i < 131072) {  // W1: K=256, N=512
    W = W1; hi = h1; lo = l1; idx = i; K = 256; N = 512;
  } else if (i < 393216) {  // W2: K=512, N=512
    W = W2; hi = h2; lo = l2; idx = i - 131072; K = 512; N = 512;
  } else {  // W3: K=512, N=256
    W = W3; hi = h3; lo = l3; idx = i - 393216; K = 512; N = 256;
  }
  const int n = idx / K, k = idx % K;
  const float w = W[(size_t)k * N + n];
  const _Float16 h = (_Float16)w;
  hi[idx] = h;
  lo[idx] = (_Float16)(w - (float)h);
}

__device__ __forceinline__ f32x4 mfma3(f16x8 ah, f16x8 al, f16x8 bh, f16x8 bl,
                                       f32x4 c) {
  c = __builtin_amdgcn_mfma_f32_16x16x32_f16(ah, bh, c, 0, 0, 0);
  c = __builtin_amdgcn_mfma_f32_16x16x32_f16(ah, bl, c, 0, 0, 0);
  c = __builtin_amdgcn_mfma_f32_16x16x32_f16(al, bh, c, 0, 0, 0);
  return c;
}

// C = A @ B, block tile 64 rows x 256 cols, BK=32 (r8 verified geometry).
// 4 waves as 2x2; wave tile 32x128 (2 m-tiles x 8 n-tiles).
// 3-product compensation (Ahi*Bhi + Ahi*Blo + Alo*Bhi, fp32 acc).
// Non-FINAL grid is 1-D with XCD-aware pairing: the two N-tile strip-mates
// (x=0,y) and (x=1,y), which read the SAME 64 A-rows, are mapped to bids
// g*16+c and g*16+c+8 -> same (bid%8) -> same XCD under round-robin
// dispatch -> second A-read hits that XCD's L2 instead of refetching.
// Epilogue: bias + activation; FINAL -> in-block softmax then fp32 out;
// else hi/lo fp16 plane scattered stores (r8-verified; coalescing attempts
// regressed - L2 write-combining handles the temporal spread better).
template <bool AF32, bool FINAL>
__global__ __launch_bounds__(256, 4) void gemm_act(
    const float* __restrict__ Af, const _Float16* __restrict__ Ahi,
    const _Float16* __restrict__ Alo, const _Float16* __restrict__ Bhi,
    const _Float16* __restrict__ Blo, const float* __restrict__ bias,
    const float* __restrict__ ap, _Float16* __restrict__ Chi,
    _Float16* __restrict__ Clo, float* __restrict__ Cout, int K, int N) {
  // sA: 8 KB = fp32 A tile 64x32 (AF32) or 2 fp16 planes 64x32 each
  // sB: 32 KB = 2 fp16 planes 256x32
  __shared__ __align__(16) _Float16 sA[4096];
  __shared__ __align__(16) _Float16 sB[16384];

  const int tid = threadIdx.x;
  const int wv = tid >> 6;
  const int lane = tid & 63;
  const int wm = wv >> 1, wn = wv & 1;
  const int m16 = lane & 15, quad = lane >> 4;
  int bx, by;
  if (FINAL) {
    bx = 0;
    by = blockIdx.x;
  } else {
    const int bid = blockIdx.x;
    by = (bid >> 4) * 8 + (bid & 7);
    bx = (bid >> 3) & 1;
  }
  const int col0 = bx * 256;
  const int row0 = by * 64;

  f32x4 acc[2][8];
  const f32x4 zero = {0.f, 0.f, 0.f, 0.f};
#pragma unroll
  for (int i = 0; i < 2; ++i)
#pragma unroll
    for (int j = 0; j < 8; ++j) acc[i][j] = zero;

  const int nk = K >> 5;
  for (int kt = 0; kt < nk; ++kt) {
    const int k0 = kt << 5;
    // ---- stage A ----
    if (AF32) {
      // 8 chunks of 1KB (8 rows x 128B); wave stages chunks 2wv, 2wv+1
      float* sAf = (float*)sA;
#pragma unroll
      for (int t = 0; t < 2; ++t) {
        const int c = wv * 2 + t;
        const int r = c * 8 + (lane >> 3);
        const size_t ga = (size_t)(row0 + r) * K + k0 + (lane & 7) * 4;
        async_ld16(Af + ga, (void*)&sAf[c * 256]);
      }
    } else {
      // per plane: 4 chunks (16 rows x 64B); wave stages chunk wv of each
      const int r = wv * 16 + (lane >> 2);
      const size_t ga = (size_t)(row0 + r) * K + k0 + (lane & 3) * 8;
      async_ld16(Ahi + ga, (void*)&sA[wv * 512]);
      async_ld16(Alo + ga, (void*)&sA[2048 + wv * 512]);
    }
    // ---- stage B: per plane 16 chunks (16 cols x 64B); wave stages 4 ----
#pragma unroll
    for (int t = 0; t < 4; ++t) {
      const int c = wv * 4 + t;
      const int col = c * 16 + (lane >> 2);
      const size_t gb = (size_t)(col0 + col) * K + k0 + (lane & 3) * 8;
      async_ld16(Bhi + gb, (void*)&sB[c * 512]);
      async_ld16(Blo + gb, (void*)&sB[8192 + c * 512]);
    }
    __syncthreads();

    // ---- A fragments ----
    f16x8 ah[2], al[2];
#pragma unroll
    for (int tm = 0; tm < 2; ++tm) {
      const int arow = wm * 32 + tm * 16 + m16;
      if (AF32) {
        const float* pa = (const float*)sA + arow * 32 + quad * 8;
        const f32x4 x0 = *(const f32x4*)pa;
        const f32x4 x1 = *(const f32x4*)(pa + 4);
#pragma unroll
        for (int j = 0; j < 4; ++j) {
          const _Float16 h0 = (_Float16)x0[j];
          ah[tm][j] = h0;
          al[tm][j] = (_Float16)(x0[j] - (float)h0);
          const _Float16 h1 = (_Float16)x1[j];
          ah[tm][4 + j] = h1;
          al[tm][4 + j] = (_Float16)(x1[j] - (float)h1);
        }
      } else {
        ah[tm] = *(const f16x8*)&sA[arow * 32 + quad * 8];
        al[tm] = *(const f16x8*)&sA[2048 + arow * 32 + quad * 8];
      }
    }
    // ---- B fragments + MFMA, n-tiles streamed ----
#pragma unroll
    for (int tn = 0; tn < 8; ++tn) {
      const int bcol = wn * 128 + tn * 16 + m16;
      const f16x8 bh = *(const f16x8*)&sB[bcol * 32 + quad * 8];
      const f16x8 bl = *(const f16x8*)&sB[8192 + bcol * 32 + quad * 8];
#pragma unroll
      for (int tm = 0; tm < 2; ++tm)
        acc[tm][tn] = mfma3(ah[tm], al[tm], bh, bl, acc[tm][tn]);
    }
    __syncthreads();
  }

  // ---- epilogue: C/D layout col=lane&15, row=quad*4+reg ----
  if (FINAL) {
    // bias + activation in place, then in-block softmax over 256 cols.
    // sA is dead after the K-loop's final barrier -> reuse for reductions.
    float* const redf = (float*)sA;        // [2 wn][64 rows]
    float* const rowm = (float*)sA + 128;  // [64] row max
    float* const rowi = (float*)sA + 192;  // [64] row 1/sum
#pragma unroll
    for (int tn = 0; tn < 8; ++tn) {
      const int col = col0 + wn * 128 + tn * 16 + m16;
      const float bs = bias[col];
      const float p0 = ap[col * 5 + 0];
      const float p1 = ap[col * 5 + 1];
      const float p2 = ap[col * 5 + 2];
      const float p3 = ap[col * 5 + 3];
      const float p4 = ap[col * 5 + 4];
#pragma unroll
      for (int tm = 0; tm < 2; ++tm)
#pragma unroll
        for (int r = 0; r < 4; ++r)
          acc[tm][tn][r] = act_f(acc[tm][tn][r] + bs, p0, p1, p2, p3, p4);
    }
#pragma unroll
    for (int tm = 0; tm < 2; ++tm)
#pragma unroll
      for (int r = 0; r < 4; ++r) {
        float m = acc[tm][0][r];
#pragma unroll
        for (int tn = 1; tn < 8; ++tn) m = fmaxf(m, acc[tm][tn][r]);
#pragma unroll
        for (int off = 1; off < 16; off <<= 1) m = fmaxf(m, __shfl_xor(m, off));
        if (m16 == 0) {
          const int rowl = wm * 32 + tm * 16 + quad * 4 + r;
          redf[wn * 64 + rowl] = m;
        }
      }
    __syncthreads();
    if (tid < 64) rowm[tid] = fmaxf(redf[tid], redf[64 + tid]);
    __syncthreads();
#pragma unroll
    for (int tm = 0; tm < 2; ++tm)
#pragma unroll
      for (int r = 0; r < 4; ++r) {
        const int rowl = wm * 32 + tm * 16 + quad * 4 + r;
        const float m = rowm[rowl];
        float s = 0.f;
#pragma unroll
        for (int tn = 0; tn < 8; ++tn) {
          const float e = __builtin_amdgcn_exp2f((acc[tm][tn][r] - m) *
                                                 1.4426950408889634f);
          acc[tm][tn][r] = e;
          s += e;
        }
#pragma unroll
        for (int off = 1; off < 16; off <<= 1) s += __shfl_xor(s, off);
        if (m16 == 0) redf[wn * 64 + rowl] = s;
      }
    __syncthreads();
    if (tid < 64) rowi[tid] = __builtin_amdgcn_rcpf(redf[tid] + redf[64 + tid]);
    __syncthreads();
#pragma unroll
    for (int tm = 0; tm < 2; ++tm)
#pragma unroll
      for (int r = 0; r < 4; ++r) {
        const int rowl = wm * 32 + tm * 16 + quad * 4 + r;
        const float inv = rowi[rowl];
#pragma unroll
        for (int tn = 0; tn < 8; ++tn) {
          const int col = col0 + wn * 128 + tn * 16 + m16;
          Cout[(size_t)(row0 + rowl) * 256 + col] = acc[tm][tn][r] * inv;
        }
      }
  } else {
#pragma unroll
    for (int tn = 0; tn < 8; ++tn) {
      const int col = col0 + wn * 128 + tn * 16 + m16;
      const float bs = bias[col];
      const float p0 = ap[col * 5 + 0];
      const float p1 = ap[col * 5 + 1];
      const float p2 = ap[col * 5 + 2];
      const float p3 = ap[col * 5 + 3];
      const float p4 = ap[col * 5 + 4];
#pragma unroll
      for (int tm = 0; tm < 2; ++tm) {
        const int row = row0 + wm * 32 + tm * 16 + quad * 4;
#pragma unroll
        for (int r = 0; r < 4; ++r) {
          const float y = act_f(acc[tm][tn][r] + bs, p0, p1, p2, p3, p4);
          const size_t o = (size_t)(row + r) * N + col;
          const _Float16 h = (_Float16)y;
          Chi[o] = h;
          Clo[o] = (_Float16)(y - (float)h);
        }
      }
    }
  }
}

extern "C" void kernel_launch(void* const* d_in, const int* in_sizes, int n_in,
                              void* d_out, int out_size, void* d_ws,
                              size_t ws_size, hipStream_t stream) {
  const float* data = (const float*)d_in[0];
  const float* W1 = (const float*)d_in[1];
  const float* b1 = (const float*)d_in[2];
  const float* a1 = (const float*)d_in[3];
  const float* W2 = (const float*)d_in[4];
  const float* b2 = (const float*)d_in[5];
  const float* a2 = (const float*)d_in[6];
  const float* W3 = (const float*)d_in[7];
  const float* b3 = (const float*)d_in[8];
  const float* a3 = (const float*)d_in[9];
  float* out = (float*)d_out;

  char* ws = (char*)d_ws;
  const size_t KB = 1024, MB = 1024 * 1024;
  _Float16* w1hi = (_Float16*)(ws + 0 * KB);  // Wt1[512][256]
  _Float16* w1lo = (_Float16*)(ws + 256 * KB);
  _Float16* w2hi = (_Float16*)(ws + 512 * KB);  // Wt2[512][512]
  _Float16* w2lo = (_Float16*)(ws + 1024 * KB);
  _Float16* w3hi = (_Float16*)(ws + 1536 * KB);  // Wt3[256][512]
  _Float16* w3lo = (_Float16*)(ws + 1792 * KB);
  // h1 hi/lo: 65536x512 fp16 = 64 MB each; h2lo 64 MB; h2hi lives in d_out
  // (row-disjoint final blocks; epilogue writes after all K-loop reads)
  _Float16* h1hi = (_Float16*)(ws + 2 * MB);
  _Float16* h1lo = (_Float16*)(ws + 2 * MB + (size_t)BATCH * 512 * 2);
  _Float16* h2lo = (_Float16*)(ws + 2 * MB + (size_t)BATCH * 512 * 4);
  _Float16* h2hi = (_Float16*)d_out;

  splitT3<<<2048, 256, 0, stream>>>(W1, w1hi, w1lo, W2, w2hi, w2lo, W3, w3hi,
                                    w3lo);

  // non-FINAL: 1-D grid 2048, XCD-paired strip-mates (see gemm_act)
  gemm_act<true, false><<<2048, 256, 0, stream>>>(
      data, nullptr, nullptr, w1hi, w1lo, b1, a1, h1hi, h1lo, nullptr, 256, 512);
  gemm_act<false, false><<<2048, 256, 0, stream>>>(
      nullptr, h1hi, h1lo, w2hi, w2lo, b2, a2, h2hi, h2lo, nullptr, 512, 512);
  gemm_act<false, true><<<1024, 256, 0, stream>>>(
      nullptr, h2hi, h2lo, w3hi, w3lo, b3, a3, nullptr, nullptr, out, 512, 256);
}